// Round 4
// baseline (1722.159 us; speedup 1.0000x reference)
//
#include <hip/hip_runtime.h>
#include <hip/hip_bf16.h>

#define NN 100000
#define NE 1600000
#define ET (NE + NN)
#define NB2 782         // buckets of 128 dst nodes
#define CAP2 2552       // slots/bucket: mean 2176, sigma ~47, +8 sigma
#define BST 8           // bucket-counter pad (ints)
#define NG 391          // src granules (src>>8): 256 nodes = 32KB of hb
#define EPB 32          // edges/thread in k_bin

typedef __hip_bfloat16 bf16;

__device__ __forceinline__ float bf2f(bf16 v){ return __bfloat162float(v); }
// order-preserving float<->uint encode for atomicMax
__device__ __forceinline__ unsigned fenc(float f){
    unsigned u = __float_as_uint(f);
    return (u & 0x80000000u) ? ~u : (u | 0x80000000u);
}
__device__ __forceinline__ float fdec(unsigned u){
    unsigned v = (u & 0x80000000u) ? (u & 0x7fffffffu) : ~u;
    return __uint_as_float(v);
}

// ---------------- CSR-lite build ----------------

__global__ void k_zero(int* __restrict__ bcnt){
    int i = blockIdx.x*256 + threadIdx.x;
    if(i < NB2*BST) bcnt[i] = 0;
}

// bin edges (incl. self loops) by dst>>7 into per-bucket regions, packed (s<<7)|ld
__global__ void __launch_bounds__(256) k_bin(const int* __restrict__ src,
        const int* __restrict__ dst, int* __restrict__ bcnt,
        int* __restrict__ binbuf){
    __shared__ int cnt[NB2];
    __shared__ int cur[NB2];
    int t = threadIdx.x;
    for(int i=t;i<NB2;i+=256) cnt[i]=0;
    __syncthreads();
    int e0 = blockIdx.x*(256*EPB);
    for(int k=0;k<EPB;k++){
        int e = e0 + k*256 + t;
        if(e < ET){
            int d = (e < NE) ? dst[e] : (e - NE);
            atomicAdd(&cnt[d>>7], 1);
        }
    }
    __syncthreads();
    for(int i=t;i<NB2;i+=256){
        int c = cnt[i];
        cur[i] = c ? atomicAdd(&bcnt[i*BST], c) : 0;
    }
    __syncthreads();
    for(int k=0;k<EPB;k++){
        int e = e0 + k*256 + t;
        if(e < ET){
            int s, d;
            if(e < NE){ s = src[e]; d = dst[e]; }
            else      { s = e - NE; d = s; }
            int b = d >> 7;
            int pos = atomicAdd(&cur[b], 1);
            if(pos < CAP2) binbuf[b*CAP2 + pos] = (s << 7) | (d & 127);
        }
    }
}

// in-place counting sort of each bucket by src granule (ent>>15 == src>>8)
__global__ void __launch_bounds__(512) k_sortb(const int* __restrict__ bcnt,
        int* __restrict__ binbuf){
    __shared__ int stage[CAP2];
    __shared__ int gc[512];
    __shared__ int gcur[NG];
    int b = blockIdx.x, t = threadIdx.x;
    int cnt = min(bcnt[b*BST], CAP2);
    int* bb = binbuf + b*CAP2;
    gc[t] = 0;
    __syncthreads();
    for(int i=t;i<cnt;i+=512) atomicAdd(&gc[bb[i]>>15], 1);
    __syncthreads();
    int v = gc[t];
    for(int off=1; off<512; off<<=1){        // Hillis-Steele inclusive scan
        int u = (t>=off) ? gc[t-off] : 0;
        __syncthreads();
        gc[t] += u;
        __syncthreads();
    }
    if(t < NG) gcur[t] = gc[t] - v;          // exclusive base per granule
    __syncthreads();
    for(int i=t;i<cnt;i+=512){
        int ent = bb[i];
        int pos = atomicAdd(&gcur[ent>>15], 1);
        stage[pos] = ent;
    }
    __syncthreads();
    for(int i=t;i<cnt;i+=512) bb[i] = stage[i];
}

// ---------------- h = x @ W, s_src, s_dst ----------------
// one wave per node; lane = output feature; W column in 64 VGPRs

template<int FPIN>
__global__ void __launch_bounds__(256) k_gemm(const void* __restrict__ xin,
        const float* __restrict__ W, const float* __restrict__ avs,
        const float* __restrict__ avd, bf16* __restrict__ hb,
        float* __restrict__ ssrc, float* __restrict__ sdst){
    int tid = threadIdx.x, wave = tid>>6, lane = tid&63;
    float Wreg[64];
    #pragma unroll
    for(int k=0;k<64;k++) Wreg[k] = W[k*64 + lane];
    float as = avs[lane], ad = avd[lane];
    int stride = gridDim.x*4;
    for(int node = blockIdx.x*4 + wave; node < NN; node += stride){
        float acc0=0.f, acc1=0.f, acc2=0.f, acc3=0.f;
        if(FPIN){
            const float4* xr = (const float4*)((const float*)xin + (size_t)node*64);
            #pragma unroll
            for(int q=0;q<16;q++){
                float4 xq = xr[q];
                acc0 += xq.x*Wreg[4*q+0];
                acc1 += xq.y*Wreg[4*q+1];
                acc2 += xq.z*Wreg[4*q+2];
                acc3 += xq.w*Wreg[4*q+3];
            }
        } else {
            const uint4* xr = (const uint4*)((const bf16*)xin + (size_t)node*64);
            #pragma unroll
            for(int q=0;q<8;q++){
                uint4 pk = xr[q];
                acc0 += __uint_as_float(pk.x<<16)        *Wreg[8*q+0];
                acc1 += __uint_as_float(pk.x&0xffff0000u)*Wreg[8*q+1];
                acc2 += __uint_as_float(pk.y<<16)        *Wreg[8*q+2];
                acc3 += __uint_as_float(pk.y&0xffff0000u)*Wreg[8*q+3];
                acc0 += __uint_as_float(pk.z<<16)        *Wreg[8*q+4];
                acc1 += __uint_as_float(pk.z&0xffff0000u)*Wreg[8*q+5];
                acc2 += __uint_as_float(pk.w<<16)        *Wreg[8*q+6];
                acc3 += __uint_as_float(pk.w&0xffff0000u)*Wreg[8*q+7];
            }
        }
        float acc = (acc0+acc1) + (acc2+acc3);
        hb[(size_t)node*64 + lane] = __float2bfloat16(acc);
        float ts = acc*as, td = acc*ad;
        #pragma unroll
        for(int m=32;m>=1;m>>=1){ ts += __shfl_xor(ts,m); td += __shfl_xor(td,m); }
        if(lane==0){ ssrc[node] = ts; sdst[node] = td; }
    }
}

// ---------------- bucket-resident attention + aggregation ----------------
// block = 128 dst nodes; LDS fp32 accumulators; edges sorted by src granule

template<int LAYER>
__global__ void __launch_bounds__(256) k_agg(const int* __restrict__ bcnt,
        const int* __restrict__ binbuf, const float* __restrict__ ssrc,
        const float* __restrict__ sdst, const bf16* __restrict__ hb,
        const float* __restrict__ bias, const float* __restrict__ Wl,
        const float* __restrict__ bl, bf16* __restrict__ out1b,
        float* __restrict__ outF){
    __shared__ float accs[128*65];     // pad 65: conflict-free ds_add
    __shared__ float alf[CAP2];
    __shared__ float sdl[128], mxf[128], den[128], rinv[128];
    __shared__ unsigned mxk[128];
    int b = blockIdx.x, t = threadIdx.x;
    int cnt = min(bcnt[b*BST], CAP2);
    const int* eb = binbuf + b*CAP2;
    int node0 = b << 7;
    if(t < 128){
        int n = node0 + t;
        sdl[t] = (n < NN) ? sdst[n] : 0.f;
        mxk[t] = 0u;
        den[t] = 0.f;
    }
    for(int i=t;i<128*65;i+=256) accs[i] = 0.f;
    __syncthreads();
    // pass 1: logits -> alf, per-dst max
    for(int i=t;i<cnt;i+=256){
        int ent = eb[i]; int s = ent>>7, ld = ent&127;
        float tt = ssrc[s] + sdl[ld];
        tt = fmaxf(tt, 0.2f*tt);           // leaky_relu, slope 0.2
        alf[i] = tt;
        atomicMax(&mxk[ld], fenc(tt));
    }
    __syncthreads();
    if(t < 128) mxf[t] = fdec(mxk[t]);
    __syncthreads();
    // pass 2: exp + per-dst denom
    for(int i=t;i<cnt;i+=256){
        int ld = eb[i] & 127;
        float p = __expf(alf[i] - mxf[ld]);
        alf[i] = p;
        atomicAdd(&den[ld], p);
    }
    __syncthreads();
    if(t < 128) rinv[t] = 1.0f/(den[t] + 1e-16f);
    __syncthreads();
    // pass 3: gather-accumulate, 8 edges per wave-iter (8 lanes x 8 channels)
    int wave = t>>6, lane = t&63, g = lane>>3, m = lane&7;
    for(int i0 = wave*8; i0 < cnt; i0 += 32){
        int ie = i0 + g;
        bool act = ie < cnt;
        int ent = act ? eb[ie] : 0;
        int s = ent>>7, ld = ent&127;
        float a = act ? alf[ie]*rinv[ld] : 0.f;
        uint4 pk = *(const uint4*)(hb + ((size_t)s<<6) + (m<<3));   // 16B: 8 bf16
        float* ap = &accs[ld*65 + (m<<3)];
        atomicAdd(ap+0, a*__uint_as_float(pk.x<<16));
        atomicAdd(ap+1, a*__uint_as_float(pk.x&0xffff0000u));
        atomicAdd(ap+2, a*__uint_as_float(pk.y<<16));
        atomicAdd(ap+3, a*__uint_as_float(pk.y&0xffff0000u));
        atomicAdd(ap+4, a*__uint_as_float(pk.z<<16));
        atomicAdd(ap+5, a*__uint_as_float(pk.z&0xffff0000u));
        atomicAdd(ap+6, a*__uint_as_float(pk.w<<16));
        atomicAdd(ap+7, a*__uint_as_float(pk.w&0xffff0000u));
    }
    __syncthreads();
    // epilogue: wave per dst row
    for(int d=wave; d<128; d+=4){
        int n = node0 + d;
        if(n < NN){
            float v = accs[d*65 + lane] + bias[lane];
            if(LAYER == 1){
                out1b[((size_t)n<<6) + lane] = __float2bfloat16(tanhf(v));
            } else {
                float r = v * Wl[lane];
                #pragma unroll
                for(int mm=32;mm>=1;mm>>=1) r += __shfl_xor(r,mm);
                if(lane==0) outF[n] = r + bl[0];
            }
        }
    }
}

// ---------------- launch ----------------

extern "C" void kernel_launch(void* const* d_in, const int* in_sizes, int n_in,
                              void* d_out, int out_size, void* d_ws, size_t ws_size,
                              hipStream_t stream) {
    const float* x   = (const float*)d_in[0];
    const int*   ei  = (const int*)d_in[1];
    const float* W1  = (const float*)d_in[2];
    const float* as1 = (const float*)d_in[3];
    const float* ad1 = (const float*)d_in[4];
    const float* b1  = (const float*)d_in[5];
    const float* W2  = (const float*)d_in[6];
    const float* as2 = (const float*)d_in[7];
    const float* ad2 = (const float*)d_in[8];
    const float* b2  = (const float*)d_in[9];
    const float* Wl  = (const float*)d_in[10];
    const float* bl  = (const float*)d_in[11];
    float* out = (float*)d_out;

    const int* srcp = ei;
    const int* dstp = ei + NE;

    // workspace ~34.4 MB (<= previously-proven footprint)
    char* w = (char*)d_ws;
    int*   binbuf = (int*)w;    w += (size_t)NB2*CAP2*4;   // 7,982,656
    bf16*  hb     = (bf16*)w;   w += (size_t)NN*64*2;      // 12,800,000
    bf16*  t1b    = (bf16*)w;   w += (size_t)NN*64*2;      // 12,800,000
    float* ssrc   = (float*)w;  w += (size_t)NN*4;
    float* sdst   = (float*)w;  w += (size_t)NN*4;
    int*   bcnt   = (int*)w;    w += (size_t)NB2*BST*4;    // 25,024

    const int nbZ   = (NB2*BST + 255)/256;               // 25
    const int nbBin = (ET + 256*EPB - 1)/(256*EPB);      // 208

    k_zero <<<nbZ, 256, 0, stream>>>(bcnt);
    k_bin  <<<nbBin, 256, 0, stream>>>(srcp, dstp, bcnt, binbuf);
    k_sortb<<<NB2, 512, 0, stream>>>(bcnt, binbuf);

    // layer 1
    k_gemm<1><<<1024, 256, 0, stream>>>((const void*)x, W1, as1, ad1, hb, ssrc, sdst);
    k_agg<1><<<NB2, 256, 0, stream>>>(bcnt, binbuf, ssrc, sdst, hb,
                                      b1, (const float*)nullptr, (const float*)nullptr,
                                      t1b, (float*)nullptr);
    // layer 2 + final linear
    k_gemm<0><<<1024, 256, 0, stream>>>((const void*)t1b, W2, as2, ad2, hb, ssrc, sdst);
    k_agg<2><<<NB2, 256, 0, stream>>>(bcnt, binbuf, ssrc, sdst, hb,
                                      b2, Wl, bl,
                                      (bf16*)nullptr, out);
}

// Round 5
// 1055.984 us; speedup vs baseline: 1.6309x; 1.6309x over previous
//
#include <hip/hip_runtime.h>
#include <hip/hip_cooperative_groups.h>
#include <hip/hip_bf16.h>

#define NN 100000
#define NE 1600000
#define ET (NE + NN)
#define NB 391          // buckets of 256 dst nodes
#define CAP 5120        // slots/bucket (mean 4352, +12 sigma)
#define BST 16          // bcnt pad: 64B per counter
#define GRID 1024       // cooperative grid: 4 blocks/CU
#define NWAVES (GRID*4)

typedef __hip_bfloat16 bf16;
namespace cg = cooperative_groups;

struct Params {
    const float* x; const int* src; const int* dst;
    const float *W1,*as1,*ad1,*b1,*W2,*as2,*ad2,*b2,*Wl,*bl;
    float* out;
    int* bcnt; int* binbuf; int* edge_src; int* rowst; int* deg;
    bf16* hb; bf16* t1b; float* ssrc; float* sdst;
};

__device__ __forceinline__ float bf2f(bf16 v){ return __bfloat162float(v); }

// ---------------- phase: bin edges by dst>>8 (int LDS atomics only) ----------------
__device__ void bin_phase(const Params& p, int* smem, int c0, int cstep){
    int* cnt = smem; int* cur = smem + NB;
    int t = threadIdx.x;
    for(int c = c0; c*2048 < ET; c += cstep){
        int e0 = c*2048;
        for(int i=t;i<NB;i+=256) cnt[i]=0;
        __syncthreads();
        #pragma unroll
        for(int k=0;k<8;k++){
            int e = e0 + k*256 + t;
            if(e < ET){ int d = (e < NE) ? p.dst[e] : (e - NE); atomicAdd(&cnt[d>>8], 1); }
        }
        __syncthreads();
        for(int i=t;i<NB;i+=256){ int cc=cnt[i]; cur[i] = cc ? atomicAdd(&p.bcnt[i*BST], cc) : 0; }
        __syncthreads();
        #pragma unroll
        for(int k=0;k<8;k++){
            int e = e0 + k*256 + t;
            if(e < ET){
                int s, d;
                if(e < NE){ s = p.src[e]; d = p.dst[e]; } else { s = e - NE; d = s; }
                int b = d >> 8;
                int pos = atomicAdd(&cur[b], 1);        // global position
                if(pos < CAP) p.binbuf[b*CAP + pos] = (s << 8) | (d & 255);
            }
        }
        __syncthreads();
    }
}

// ---------------- phase: per-bucket CSR build (fused prefix over buckets) ----------------
__device__ void build_phase(const Params& p, int* smem, int b0, int bstep){
    int* lsrc  = smem;          // 5120
    int* ldeg  = smem + 5120;   // 256
    int* lscan = smem + 5376;   // 256
    int* lcur  = smem + 5632;   // 256
    int* red   = smem + 5888;   // 256
    int t = threadIdx.x;
    for(int b = b0; b < NB; b += bstep){
        int cnt = min(p.bcnt[b*BST], CAP);
        // base = sum of counts of buckets < b (bcnt is tiny, L2-hot)
        int part = 0;
        for(int i=t;i<b;i+=256) part += min(p.bcnt[i*BST], CAP);
        red[t] = part; __syncthreads();
        for(int off=128; off>=1; off>>=1){ if(t<off) red[t]+=red[t+off]; __syncthreads(); }
        int base = red[0];
        __syncthreads();
        ldeg[t] = 0; __syncthreads();
        const int* bb = p.binbuf + b*CAP;
        for(int i=t;i<cnt;i+=256) atomicAdd(&ldeg[bb[i] & 255], 1);
        __syncthreads();
        int dv = ldeg[t]; lscan[t] = dv; __syncthreads();
        for(int off=1; off<256; off<<=1){
            int u = (t>=off) ? lscan[t-off] : 0;
            __syncthreads(); lscan[t] += u; __syncthreads();
        }
        int excl = lscan[t] - dv; lcur[t] = excl;
        int node = b*256 + t;
        if(node < NN){ p.rowst[node] = base + excl; p.deg[node] = dv; }
        __syncthreads();
        for(int i=t;i<cnt;i+=256){
            int ent = bb[i];
            int pos = atomicAdd(&lcur[ent & 255], 1);
            lsrc[pos] = ent >> 8;
        }
        __syncthreads();
        for(int i=t;i<cnt;i+=256) p.edge_src[base+i] = lsrc[i];
        __syncthreads();
    }
}

// ---------------- phase: h = x@W, s_src, s_dst (wave per node) ----------------
template<int FPIN>
__device__ void gemm_phase(const void* xin, const float* W, const float* avs,
        const float* avd, bf16* hb, float* ssrc, float* sdst, int w0, int wstep){
    int lane = threadIdx.x & 63;
    float Wreg[64];
    #pragma unroll
    for(int k=0;k<64;k++) Wreg[k] = W[k*64 + lane];
    float as = avs[lane], ad = avd[lane];
    for(int node = w0; node < NN; node += wstep){
        float acc0=0.f, acc1=0.f, acc2=0.f, acc3=0.f;
        if(FPIN){
            const float4* xr = (const float4*)((const float*)xin + (size_t)node*64);
            #pragma unroll
            for(int q=0;q<16;q++){
                float4 xq = xr[q];
                acc0 += xq.x*Wreg[4*q+0];
                acc1 += xq.y*Wreg[4*q+1];
                acc2 += xq.z*Wreg[4*q+2];
                acc3 += xq.w*Wreg[4*q+3];
            }
        } else {
            const uint4* xr = (const uint4*)((const bf16*)xin + (size_t)node*64);
            #pragma unroll
            for(int q=0;q<8;q++){
                uint4 pk = xr[q];
                acc0 += __uint_as_float(pk.x<<16)        *Wreg[8*q+0];
                acc1 += __uint_as_float(pk.x&0xffff0000u)*Wreg[8*q+1];
                acc2 += __uint_as_float(pk.y<<16)        *Wreg[8*q+2];
                acc3 += __uint_as_float(pk.y&0xffff0000u)*Wreg[8*q+3];
                acc0 += __uint_as_float(pk.z<<16)        *Wreg[8*q+4];
                acc1 += __uint_as_float(pk.z&0xffff0000u)*Wreg[8*q+5];
                acc2 += __uint_as_float(pk.w<<16)        *Wreg[8*q+6];
                acc3 += __uint_as_float(pk.w&0xffff0000u)*Wreg[8*q+7];
            }
        }
        float acc = (acc0+acc1) + (acc2+acc3);
        hb[(size_t)node*64 + lane] = __float2bfloat16(acc);
        float ts = acc*as, td = acc*ad;
        #pragma unroll
        for(int m=32;m>=1;m>>=1){ ts += __shfl_xor(ts,m); td += __shfl_xor(td,m); }
        if(lane==0){ ssrc[node] = ts; sdst[node] = td; }
    }
}

// ---------------- phase: attention + aggregation (wave per dst, 8-deep MLP) ----------------
template<int LAYER>
__device__ void agg_phase(const Params& p, const bf16* hb, const float* bias,
        bf16* out1b, float* outF, int w0, int wstep){
    int lane = threadIdx.x & 63;
    for(int wid = w0; wid < NN; wid += wstep){
        int rs = p.rowst[wid];
        int d  = p.deg[wid];
        float sd = p.sdst[wid];
        float acc = 0.f;
        if(d <= 64){
            int s = 0; float e = -1e30f;
            if(lane < d){
                s = p.edge_src[rs + lane];
                float t = p.ssrc[s] + sd;
                e = fmaxf(t, 0.2f*t);               // leaky_relu
            }
            float mx = e;
            #pragma unroll
            for(int m=32;m>=1;m>>=1) mx = fmaxf(mx, __shfl_xor(mx,m));
            float pr = (lane < d) ? __expf(e - mx) : 0.f;
            float sm = pr;
            #pragma unroll
            for(int m=32;m>=1;m>>=1) sm += __shfl_xor(sm,m);
            float alpha = pr * (1.0f/(sm + 1e-16f));
            for(int j0=0; j0<d; j0+=8){             // 8 independent row loads in flight
                int sk[8]; float ak[8]; bf16 hk[8];
                #pragma unroll
                for(int k=0;k<8;k++) if(j0+k < d){ sk[k]=__shfl(s,j0+k); ak[k]=__shfl(alpha,j0+k); }
                #pragma unroll
                for(int k=0;k<8;k++) if(j0+k < d) hk[k] = hb[((size_t)sk[k]<<6) + lane];
                #pragma unroll
                for(int k=0;k<8;k++) if(j0+k < d) acc += ak[k]*bf2f(hk[k]);
            }
        } else {
            float lmax = -1e30f;
            for(int j=lane; j<d; j+=64){
                int sj = p.edge_src[rs+j];
                float t = p.ssrc[sj] + sd;
                lmax = fmaxf(lmax, fmaxf(t, 0.2f*t));
            }
            #pragma unroll
            for(int m=32;m>=1;m>>=1) lmax = fmaxf(lmax, __shfl_xor(lmax,m));
            float lsum = 0.f;
            for(int j=lane; j<d; j+=64){
                int sj = p.edge_src[rs+j];
                float t = p.ssrc[sj] + sd;
                lsum += __expf(fmaxf(t, 0.2f*t) - lmax);
            }
            #pragma unroll
            for(int m=32;m>=1;m>>=1) lsum += __shfl_xor(lsum,m);
            float inv = 1.0f/(lsum + 1e-16f);
            for(int j=0;j<d;j++){
                int sj = p.edge_src[rs+j];
                float t = p.ssrc[sj] + sd;
                acc += __expf(fmaxf(t, 0.2f*t) - lmax)*inv * bf2f(hb[((size_t)sj<<6) + lane]);
            }
        }
        if(LAYER == 1){
            out1b[((size_t)wid<<6) + lane] = __float2bfloat16(tanhf(acc + bias[lane]));
        } else {
            float r = (acc + bias[lane]) * p.Wl[lane];
            #pragma unroll
            for(int m=32;m>=1;m>>=1) r += __shfl_xor(r,m);
            if(lane==0) outF[wid] = r + p.bl[0];
        }
    }
}

// ---------------- fused cooperative kernel ----------------
__global__ void __launch_bounds__(256, 4) k_fused(Params p){
    __shared__ int smem[6144];      // 24.6 KB: union of bin(782) / build(6144)
    cg::grid_group g = cg::this_grid();
    int wave = threadIdx.x >> 6;
    int gw = blockIdx.x*4 + wave;
    bin_phase(p, smem, blockIdx.x, GRID);
    g.sync();
    build_phase(p, smem, blockIdx.x, GRID);
    g.sync();                                   // binbuf dead; hb may be written now
    gemm_phase<1>((const void*)p.x, p.W1, p.as1, p.ad1, p.hb, p.ssrc, p.sdst, gw, NWAVES);
    g.sync();
    agg_phase<1>(p, p.hb, p.b1, p.t1b, (float*)nullptr, gw, NWAVES);
    g.sync();
    gemm_phase<0>((const void*)p.t1b, p.W2, p.as2, p.ad2, p.hb, p.ssrc, p.sdst, gw, NWAVES);
    g.sync();
    agg_phase<2>(p, p.hb, p.b2, (bf16*)nullptr, p.out, gw, NWAVES);
}

// ---------------- standalone fallbacks (same device code, ordinary launches) ----------------
__global__ void __launch_bounds__(256) k_bin_s(Params p){
    __shared__ int smem[782];
    bin_phase(p, smem, blockIdx.x, gridDim.x);
}
__global__ void __launch_bounds__(256) k_build_s(Params p){
    __shared__ int smem[6144];
    build_phase(p, smem, blockIdx.x, gridDim.x);
}
template<int F>
__global__ void __launch_bounds__(256) k_gemm_s(Params p){
    int gw = blockIdx.x*4 + (threadIdx.x>>6);
    if(F) gemm_phase<1>((const void*)p.x,  p.W1, p.as1, p.ad1, p.hb, p.ssrc, p.sdst, gw, gridDim.x*4);
    else  gemm_phase<0>((const void*)p.t1b, p.W2, p.as2, p.ad2, p.hb, p.ssrc, p.sdst, gw, gridDim.x*4);
}
template<int L>
__global__ void __launch_bounds__(256) k_agg_s(Params p){
    int gw = blockIdx.x*4 + (threadIdx.x>>6);
    if(L==1) agg_phase<1>(p, p.hb, p.b1, p.t1b, (float*)nullptr, gw, gridDim.x*4);
    else     agg_phase<2>(p, p.hb, p.b2, (bf16*)nullptr, p.out, gw, gridDim.x*4);
}

// ---------------- launch ----------------
extern "C" void kernel_launch(void* const* d_in, const int* in_sizes, int n_in,
                              void* d_out, int out_size, void* d_ws, size_t ws_size,
                              hipStream_t stream) {
    Params p;
    p.x   = (const float*)d_in[0];
    p.src = (const int*)d_in[1];
    p.dst = ((const int*)d_in[1]) + NE;
    p.W1  = (const float*)d_in[2];  p.as1 = (const float*)d_in[3];
    p.ad1 = (const float*)d_in[4];  p.b1  = (const float*)d_in[5];
    p.W2  = (const float*)d_in[6];  p.as2 = (const float*)d_in[7];
    p.ad2 = (const float*)d_in[8];  p.b2  = (const float*)d_in[9];
    p.Wl  = (const float*)d_in[10]; p.bl  = (const float*)d_in[11];
    p.out = (float*)d_out;

    char* w = (char*)d_ws;
    p.edge_src = (int*)w;   w += (size_t)ET*4;        //  6.8 MB
    p.hb       = (bf16*)w;  w += (size_t)NN*64*2;     // 12.8 MB
    p.t1b      = (bf16*)w;  w += (size_t)NN*64*2;     // 12.8 MB
    p.rowst    = (int*)w;   w += (size_t)NN*4;
    p.deg      = (int*)w;   w += (size_t)NN*4;
    p.ssrc     = (float*)w; w += (size_t)NN*4;
    p.sdst     = (float*)w; w += (size_t)NN*4;
    p.bcnt     = (int*)w;   w += (size_t)NB*BST*4;
    p.binbuf   = (int*)p.hb;    // aliases hb; dead before gemm_phase<1> writes

    hipMemsetAsync(p.bcnt, 0, (size_t)NB*BST*4, stream);

    void* args[] = { &p };
    hipError_t err = hipLaunchCooperativeKernel((const void*)k_fused,
                                                dim3(GRID), dim3(256), args, 0, stream);
    if(err != hipSuccess){
        (void)hipGetLastError();    // clear; deterministic fallback path
        const int nbBin = (ET + 2047)/2048;     // 831
        k_bin_s  <<<nbBin, 256, 0, stream>>>(p);
        k_build_s<<<NB,    256, 0, stream>>>(p);
        k_gemm_s<1><<<1024,  256, 0, stream>>>(p);
        k_agg_s<1><<<25000, 256, 0, stream>>>(p);
        k_gemm_s<0><<<1024,  256, 0, stream>>>(p);
        k_agg_s<2><<<25000, 256, 0, stream>>>(p);
    }
}

// Round 6
// 371.225 us; speedup vs baseline: 4.6391x; 2.8446x over previous
//
#include <hip/hip_runtime.h>
#include <hip/hip_bf16.h>

#define NN 100000
#define NE 1600000
#define ET (NE + NN)
#define NB 391          // buckets of 256 dst nodes
#define CAP 5120        // slots/bucket (mean 4352, +12 sigma)
#define BST 16          // bcnt pad: 64B per counter

typedef __hip_bfloat16 bf16;

__device__ __forceinline__ float bf2f(bf16 v){ return __bfloat162float(v); }
__device__ __forceinline__ unsigned short bfbits(float v){
    bf16 b = __float2bfloat16(v);
    return *(unsigned short*)&b;
}

// ---------------- CSR build: bin by dst>>8 ----------------
__global__ void __launch_bounds__(256) k_bin(const int* __restrict__ src,
        const int* __restrict__ dst, int* __restrict__ bcnt,
        int* __restrict__ binbuf){
    __shared__ int cnt[NB];
    __shared__ int cur[NB];
    int t = threadIdx.x;
    for(int i=t;i<NB;i+=256) cnt[i]=0;
    __syncthreads();
    int e0 = blockIdx.x*2048;
    #pragma unroll
    for(int k=0;k<8;k++){
        int e = e0 + k*256 + t;
        if(e < ET){ int d = (e < NE) ? dst[e] : (e - NE); atomicAdd(&cnt[d>>8], 1); }
    }
    __syncthreads();
    for(int i=t;i<NB;i+=256){ int c=cnt[i]; cur[i] = c ? atomicAdd(&bcnt[i*BST], c) : 0; }
    __syncthreads();
    #pragma unroll
    for(int k=0;k<8;k++){
        int e = e0 + k*256 + t;
        if(e < ET){
            int s, d;
            if(e < NE){ s = src[e]; d = dst[e]; } else { s = e - NE; d = s; }
            int b = d >> 8;
            int pos = atomicAdd(&cur[b], 1);
            if(pos < CAP) binbuf[b*CAP + pos] = (s << 8) | (d & 255);
        }
    }
}

// ---------------- CSR build: per-bucket dense build (base prefix fused) ----------------
__global__ void __launch_bounds__(256) k_build(const int* __restrict__ bcnt,
        const int* __restrict__ binbuf, int* __restrict__ edge_src,
        int* __restrict__ rowst, int* __restrict__ deg){
    __shared__ int lsrc[CAP];
    __shared__ int ldeg[256], lscan[256], lcur[256], red[256];
    int b = blockIdx.x, t = threadIdx.x;
    int cnt = min(bcnt[b*BST], CAP);
    // base = sum of counts of buckets < b  (bcnt tiny, L2-hot; <=2 iters/lane)
    int part = 0;
    for(int i=t;i<b;i+=256) part += min(bcnt[i*BST], CAP);
    red[t] = part; __syncthreads();
    for(int off=128; off>=1; off>>=1){ if(t<off) red[t]+=red[t+off]; __syncthreads(); }
    int base = red[0];
    __syncthreads();
    ldeg[t] = 0; __syncthreads();
    const int* bb = binbuf + b*CAP;
    for(int i=t;i<cnt;i+=256) atomicAdd(&ldeg[bb[i] & 255], 1);
    __syncthreads();
    int dv = ldeg[t]; lscan[t] = dv; __syncthreads();
    for(int off=1; off<256; off<<=1){
        int u = (t>=off) ? lscan[t-off] : 0;
        __syncthreads(); lscan[t] += u; __syncthreads();
    }
    int excl = lscan[t] - dv; lcur[t] = excl;
    int node = b*256 + t;
    if(node < NN){ rowst[node] = base + excl; deg[node] = dv; }
    __syncthreads();
    for(int i=t;i<cnt;i+=256){
        int ent = bb[i];
        int pos = atomicAdd(&lcur[ent & 255], 1);
        lsrc[pos] = ent >> 8;
    }
    __syncthreads();
    for(int i=t;i<cnt;i+=256) edge_src[base+i] = lsrc[i];
}

// ---------------- h = x@W, s_src, s_dst (wave per node) ----------------
template<int FPIN>
__global__ void __launch_bounds__(256) k_gemm(const void* __restrict__ xin,
        const float* __restrict__ W, const float* __restrict__ avs,
        const float* __restrict__ avd, bf16* __restrict__ hb,
        float* __restrict__ ssrc, float* __restrict__ sdst){
    int tid = threadIdx.x, wave = tid>>6, lane = tid&63;
    float Wreg[64];
    #pragma unroll
    for(int k=0;k<64;k++) Wreg[k] = W[k*64 + lane];
    float as = avs[lane], ad = avd[lane];
    int stride = gridDim.x*4;
    for(int node = blockIdx.x*4 + wave; node < NN; node += stride){
        float acc0=0.f, acc1=0.f, acc2=0.f, acc3=0.f;
        if(FPIN){
            const float4* xr = (const float4*)((const float*)xin + (size_t)node*64);
            #pragma unroll
            for(int q=0;q<16;q++){
                float4 xq = xr[q];
                acc0 += xq.x*Wreg[4*q+0];
                acc1 += xq.y*Wreg[4*q+1];
                acc2 += xq.z*Wreg[4*q+2];
                acc3 += xq.w*Wreg[4*q+3];
            }
        } else {
            const uint4* xr = (const uint4*)((const bf16*)xin + (size_t)node*64);
            #pragma unroll
            for(int q=0;q<8;q++){
                uint4 pk = xr[q];
                acc0 += __uint_as_float(pk.x<<16)        *Wreg[8*q+0];
                acc1 += __uint_as_float(pk.x&0xffff0000u)*Wreg[8*q+1];
                acc2 += __uint_as_float(pk.y<<16)        *Wreg[8*q+2];
                acc3 += __uint_as_float(pk.y&0xffff0000u)*Wreg[8*q+3];
                acc0 += __uint_as_float(pk.z<<16)        *Wreg[8*q+4];
                acc1 += __uint_as_float(pk.z&0xffff0000u)*Wreg[8*q+5];
                acc2 += __uint_as_float(pk.w<<16)        *Wreg[8*q+6];
                acc3 += __uint_as_float(pk.w&0xffff0000u)*Wreg[8*q+7];
            }
        }
        float acc = (acc0+acc1) + (acc2+acc3);
        hb[(size_t)node*64 + lane] = __float2bfloat16(acc);
        float ts = acc*as, td = acc*ad;
        #pragma unroll
        for(int m=32;m>=1;m>>=1){ ts += __shfl_xor(ts,m); td += __shfl_xor(td,m); }
        if(lane==0){ ssrc[node] = ts; sdst[node] = td; }
    }
}

// ---------------- attention + aggregation ----------------
// wave per dst node; gather vectorized: uint2/lane = 4 rows (512B) per iteration.
// lane group g=lane>>4 selects row, lane&15 selects 8B channel chunk.
// Accumulators per lane: channels c0..c0+3, c0=(lane&15)*4; groups folded at end.

template<int LAYER>
__global__ void __launch_bounds__(256) k_agg(
        const int* __restrict__ rowst, const int* __restrict__ deg,
        const int* __restrict__ edge_src,
        const float* __restrict__ ssrc, const float* __restrict__ sdst,
        const bf16* __restrict__ hb,
        const float* __restrict__ bias, const float* __restrict__ Wl,
        const float* __restrict__ bl,
        bf16* __restrict__ out1b, float* __restrict__ outF){
    int wid  = (blockIdx.x*256 + threadIdx.x) >> 6;
    int lane = threadIdx.x & 63;
    if(wid >= NN) return;
    int rs = rowst[wid];
    int d  = deg[wid];
    float sd = sdst[wid];
    int grp = lane >> 4;
    int ch  = lane & 15;                 // channel chunk: bf16 channels ch*4 .. ch*4+3
    float a0=0.f, a1=0.f, a2=0.f, a3=0.f;

    if(d <= 64){
        int s = 0; float e = -1e30f;
        if(lane < d){
            s = edge_src[rs + lane];
            float t = ssrc[s] + sd;
            e = fmaxf(t, 0.2f*t);        // leaky_relu
        }
        float mx = e;
        #pragma unroll
        for(int m=32;m>=1;m>>=1) mx = fmaxf(mx, __shfl_xor(mx,m));
        float pr = (lane < d) ? __expf(e - mx) : 0.f;
        float sm = pr;
        #pragma unroll
        for(int m=32;m>=1;m>>=1) sm += __shfl_xor(sm,m);
        float alpha = pr * (1.0f/(sm + 1e-16f));
        for(int i0=0; i0<d; i0+=4){
            int r  = i0 + grp;
            int rr = (r < d) ? r : 0;
            float a = __shfl(alpha, rr);
            int  sj = __shfl(s, rr);
            if(r >= d) a = 0.f;
            uint2 pk = ((const uint2*)(hb + ((size_t)sj<<6)))[ch];
            a0 += a*__uint_as_float(pk.x<<16);
            a1 += a*__uint_as_float(pk.x&0xffff0000u);
            a2 += a*__uint_as_float(pk.y<<16);
            a3 += a*__uint_as_float(pk.y&0xffff0000u);
        }
    } else {
        // generic path (d>64): two-pass softmax, then 64-edge chunks
        float lmax = -1e30f;
        for(int j=lane; j<d; j+=64){
            int sj = edge_src[rs+j];
            float t = ssrc[sj] + sd;
            lmax = fmaxf(lmax, fmaxf(t, 0.2f*t));
        }
        #pragma unroll
        for(int m=32;m>=1;m>>=1) lmax = fmaxf(lmax, __shfl_xor(lmax,m));
        float lsum = 0.f;
        for(int j=lane; j<d; j+=64){
            int sj = edge_src[rs+j];
            float t = ssrc[sj] + sd;
            lsum += __expf(fmaxf(t, 0.2f*t) - lmax);
        }
        #pragma unroll
        for(int m=32;m>=1;m>>=1) lsum += __shfl_xor(lsum,m);
        float inv = 1.0f/(lsum + 1e-16f);
        for(int cb=0; cb<d; cb+=64){
            int s2 = 0; float al = 0.f;
            int j = cb + lane;
            if(j < d){
                s2 = edge_src[rs+j];
                float t = ssrc[s2] + sd;
                al = __expf(fmaxf(t, 0.2f*t) - lmax) * inv;
            }
            int dd = min(d - cb, 64);
            for(int i0=0; i0<dd; i0+=4){
                int r  = i0 + grp;
                int rr = (r < dd) ? r : 0;
                float a = __shfl(al, rr);
                int  sj = __shfl(s2, rr);
                if(r >= dd) a = 0.f;
                uint2 pk = ((const uint2*)(hb + ((size_t)sj<<6)))[ch];
                a0 += a*__uint_as_float(pk.x<<16);
                a1 += a*__uint_as_float(pk.x&0xffff0000u);
                a2 += a*__uint_as_float(pk.y<<16);
                a3 += a*__uint_as_float(pk.y&0xffff0000u);
            }
        }
    }

    // fold the 4 row-groups: after this every lane holds totals for its chunk
    a0 += __shfl_xor(a0,32); a1 += __shfl_xor(a1,32);
    a2 += __shfl_xor(a2,32); a3 += __shfl_xor(a3,32);
    a0 += __shfl_xor(a0,16); a1 += __shfl_xor(a1,16);
    a2 += __shfl_xor(a2,16); a3 += __shfl_xor(a3,16);

    float4 bv = ((const float4*)bias)[ch];
    if(LAYER == 1){
        if(lane < 16){
            float v0 = tanhf(a0 + bv.x);
            float v1 = tanhf(a1 + bv.y);
            float v2 = tanhf(a2 + bv.z);
            float v3 = tanhf(a3 + bv.w);
            uint2 o;
            o.x = (unsigned)bfbits(v0) | ((unsigned)bfbits(v1) << 16);
            o.y = (unsigned)bfbits(v2) | ((unsigned)bfbits(v3) << 16);
            ((uint2*)(out1b + ((size_t)wid<<6)))[ch] = o;
        }
    } else {
        float4 wv = ((const float4*)Wl)[ch];
        float r = (a0+bv.x)*wv.x + (a1+bv.y)*wv.y + (a2+bv.z)*wv.z + (a3+bv.w)*wv.w;
        r += __shfl_xor(r,8); r += __shfl_xor(r,4);
        r += __shfl_xor(r,2); r += __shfl_xor(r,1);
        if(lane == 0) outF[wid] = r + bl[0];
    }
}

// ---------------- launch ----------------
extern "C" void kernel_launch(void* const* d_in, const int* in_sizes, int n_in,
                              void* d_out, int out_size, void* d_ws, size_t ws_size,
                              hipStream_t stream) {
    const float* x   = (const float*)d_in[0];
    const int*   ei  = (const int*)d_in[1];
    const float* W1  = (const float*)d_in[2];
    const float* as1 = (const float*)d_in[3];
    const float* ad1 = (const float*)d_in[4];
    const float* b1  = (const float*)d_in[5];
    const float* W2  = (const float*)d_in[6];
    const float* as2 = (const float*)d_in[7];
    const float* ad2 = (const float*)d_in[8];
    const float* b2  = (const float*)d_in[9];
    const float* Wl  = (const float*)d_in[10];
    const float* bl  = (const float*)d_in[11];
    float* out = (float*)d_out;

    const int* srcp = ei;
    const int* dstp = ei + NE;

    char* w = (char*)d_ws;
    int*   edge_src = (int*)w;  w += (size_t)ET*4;      //  6.8 MB
    bf16*  hb       = (bf16*)w; w += (size_t)NN*64*2;   // 12.8 MB
    bf16*  t1b      = (bf16*)w; w += (size_t)NN*64*2;   // 12.8 MB
    int*   rowst    = (int*)w;  w += (size_t)NN*4;
    int*   deg      = (int*)w;  w += (size_t)NN*4;
    float* ssrc     = (float*)w; w += (size_t)NN*4;
    float* sdst     = (float*)w; w += (size_t)NN*4;
    int*   bcnt     = (int*)w;  w += (size_t)NB*BST*4;
    int*   binbuf   = (int*)hb;     // aliases hb: dead before k_gemm<1> writes

    const int nbBin = (ET + 2047)/2048;     // 831
    const int nbA   = (NN + 3)/4;           // 25000

    hipMemsetAsync(bcnt, 0, (size_t)NB*BST*4, stream);
    k_bin  <<<nbBin, 256, 0, stream>>>(srcp, dstp, bcnt, binbuf);
    k_build<<<NB,    256, 0, stream>>>(bcnt, binbuf, edge_src, rowst, deg);

    // layer 1
    k_gemm<1><<<1024, 256, 0, stream>>>((const void*)x, W1, as1, ad1, hb, ssrc, sdst);
    k_agg<1><<<nbA, 256, 0, stream>>>(rowst, deg, edge_src, ssrc, sdst, hb,
                                      b1, (const float*)nullptr, (const float*)nullptr,
                                      t1b, (float*)nullptr);
    // layer 2 + final linear
    k_gemm<0><<<1024, 256, 0, stream>>>((const void*)t1b, W2, as2, ad2, hb, ssrc, sdst);
    k_agg<2><<<nbA, 256, 0, stream>>>(rowst, deg, edge_src, ssrc, sdst, hb,
                                      b2, Wl, bl,
                                      (bf16*)nullptr, out);
}